// Round 3
// baseline (315.623 us; speedup 1.0000x reference)
//
#include <hip/hip_runtime.h>

// out[b,h,w,c] = sum_j w[j,c] * t_j[b,h,w,c]
// N = 16,777,216 f32 -> 4,194,304 float4s.
// R2: same as R1 but using a native clang vector type so
// __builtin_nontemporal_store compiles (HIP float4 is a struct, rejected).
// 4 float4s per thread, grid-stride with stride % 32 == 0 so the per-channel
// w vectors are loop-invariant; 20 independent loads in flight per thread.

typedef float fvec4 __attribute__((ext_vector_type(4)));

#define NPER 4
#define BLOCKS 4096
#define THREADS 256
#define STRIDE (BLOCKS * THREADS)   // 1,048,576 fvec4s; % 32 == 0

__global__ __launch_bounds__(THREADS) void merge5_kernel(
    const float* __restrict__ t1, const float* __restrict__ t2,
    const float* __restrict__ t3, const float* __restrict__ t4,
    const float* __restrict__ t5, const float* __restrict__ w,
    float* __restrict__ out)
{
    const int tid = blockIdx.x * THREADS + threadIdx.x;

    // channel base for this lane's float4 (invariant across iterations)
    const int c4 = (tid & 31) << 2;
    const fvec4 w0 = *(const fvec4*)(w + 0 * 128 + c4);
    const fvec4 w1 = *(const fvec4*)(w + 1 * 128 + c4);
    const fvec4 w2 = *(const fvec4*)(w + 2 * 128 + c4);
    const fvec4 w3 = *(const fvec4*)(w + 3 * 128 + c4);
    const fvec4 w4 = *(const fvec4*)(w + 4 * 128 + c4);

    fvec4 a[NPER], b[NPER], c[NPER], d[NPER], e[NPER];

#pragma unroll
    for (int i = 0; i < NPER; ++i) {
        const int idx = tid + i * STRIDE;
        a[i] = ((const fvec4*)t1)[idx];
        b[i] = ((const fvec4*)t2)[idx];
        c[i] = ((const fvec4*)t3)[idx];
        d[i] = ((const fvec4*)t4)[idx];
        e[i] = ((const fvec4*)t5)[idx];
    }

#pragma unroll
    for (int i = 0; i < NPER; ++i) {
        fvec4 r = a[i] * w0 + b[i] * w1 + c[i] * w2 + d[i] * w3 + e[i] * w4;
        const int idx = tid + i * STRIDE;
        __builtin_nontemporal_store(r, (fvec4*)out + idx);
    }
}

extern "C" void kernel_launch(void* const* d_in, const int* in_sizes, int n_in,
                              void* d_out, int out_size, void* d_ws, size_t ws_size,
                              hipStream_t stream) {
    const float* t1 = (const float*)d_in[0];
    const float* t2 = (const float*)d_in[1];
    const float* t3 = (const float*)d_in[2];
    const float* t4 = (const float*)d_in[3];
    const float* t5 = (const float*)d_in[4];
    const float* w  = (const float*)d_in[5];
    float* out = (float*)d_out;

    // out_size = 16,777,216 -> nvec = 4,194,304 = BLOCKS*THREADS*NPER exactly.
    merge5_kernel<<<BLOCKS, THREADS, 0, stream>>>(t1, t2, t3, t4, t5, w, out);
}

// Round 4
// 307.598 us; speedup vs baseline: 1.0261x; 1.0261x over previous
//
#include <hip/hip_runtime.h>

// out[b,h,w,c] = sum_j w[j,c] * t_j[b,h,w,c]
// N = 16,777,216 f32 = 4,194,304 float4.
// R4: persistent grid-stride kernel (2048 blocks = 8 wg/CU, 8 iters/thread)
// with a depth-2 software pipeline: issue iteration i+1's 5 loads before
// computing iteration i, so ~10 loads stay outstanding per wave in steady
// state. Plain (cached) stores — NT stores regressed in R3.

typedef float fvec4 __attribute__((ext_vector_type(4)));

#define THREADS 256
#define BLOCKS  2048
#define NITER   8
#define STRIDE  (BLOCKS * THREADS)   // 524,288 float4s; % 32 == 0 -> c4 invariant

__global__ __launch_bounds__(THREADS) void merge5_kernel(
    const float* __restrict__ t1, const float* __restrict__ t2,
    const float* __restrict__ t3, const float* __restrict__ t4,
    const float* __restrict__ t5, const float* __restrict__ w,
    float* __restrict__ out)
{
    const int tid = blockIdx.x * THREADS + threadIdx.x;

    // per-lane channel base (loop-invariant since STRIDE % 32 == 0)
    const int c4 = (tid & 31) << 2;
    const fvec4 w0 = *(const fvec4*)(w + 0 * 128 + c4);
    const fvec4 w1 = *(const fvec4*)(w + 1 * 128 + c4);
    const fvec4 w2 = *(const fvec4*)(w + 2 * 128 + c4);
    const fvec4 w3 = *(const fvec4*)(w + 3 * 128 + c4);
    const fvec4 w4 = *(const fvec4*)(w + 4 * 128 + c4);

    // prologue: loads for iteration 0
    fvec4 a0 = ((const fvec4*)t1)[tid];
    fvec4 b0 = ((const fvec4*)t2)[tid];
    fvec4 c0 = ((const fvec4*)t3)[tid];
    fvec4 d0 = ((const fvec4*)t4)[tid];
    fvec4 e0 = ((const fvec4*)t5)[tid];

#pragma unroll
    for (int i = 0; i < NITER; ++i) {
        const int idx  = tid + i * STRIDE;
        fvec4 a1, b1, c1, d1, e1;
        if (i + 1 < NITER) {
            const int nidx = idx + STRIDE;
            a1 = ((const fvec4*)t1)[nidx];
            b1 = ((const fvec4*)t2)[nidx];
            c1 = ((const fvec4*)t3)[nidx];
            d1 = ((const fvec4*)t4)[nidx];
            e1 = ((const fvec4*)t5)[nidx];
        }
        fvec4 r = a0 * w0 + b0 * w1 + c0 * w2 + d0 * w3 + e0 * w4;
        ((fvec4*)out)[idx] = r;
        a0 = a1; b0 = b1; c0 = c1; d0 = d1; e0 = e1;
    }
}

extern "C" void kernel_launch(void* const* d_in, const int* in_sizes, int n_in,
                              void* d_out, int out_size, void* d_ws, size_t ws_size,
                              hipStream_t stream) {
    const float* t1 = (const float*)d_in[0];
    const float* t2 = (const float*)d_in[1];
    const float* t3 = (const float*)d_in[2];
    const float* t4 = (const float*)d_in[3];
    const float* t5 = (const float*)d_in[4];
    const float* w  = (const float*)d_in[5];
    float* out = (float*)d_out;

    // out_size/4 = 4,194,304 = BLOCKS*THREADS*NITER exactly.
    merge5_kernel<<<BLOCKS, THREADS, 0, stream>>>(t1, t2, t3, t4, t5, w, out);
}